// Round 1
// baseline (805.314 us; speedup 1.0000x reference)
//
#include <hip/hip_runtime.h>
#include <cmath>

#define NPTS   1048576
#define NLVL   16
#define TMASK  ((1u << 19) - 1u)
#define P1     2654435761u
#define P2     805459861u

struct ResArr { int r[NLVL]; };

__global__ __launch_bounds__(256) void hashgrid_enc(
    const float* __restrict__ x,
    const float* __restrict__ table,
    float* __restrict__ out,
    ResArr res)
{
    const int n = blockIdx.x * 256 + threadIdx.x;
    if (n >= NPTS) return;

    const float px = x[3 * n + 0];
    const float py = x[3 * n + 1];
    const float pz = x[3 * n + 2];

    float acc[2 * NLVL];

#pragma unroll
    for (int lvl = 0; lvl < NLVL; ++lvl) {
        const float rf = (float)res.r[lvl];
        // scaled coords, floor, trilerp weights — must match fp32 reference exactly
        const float xs0 = px * rf, xs1 = py * rf, xs2 = pz * rf;
        const float f0 = floorf(xs0), f1 = floorf(xs1), f2 = floorf(xs2);
        const float w0 = xs0 - f0, w1 = xs1 - f1, w2 = xs2 - f2;

        const uint32_t i0 = (uint32_t)f0;
        const uint32_t i1 = (uint32_t)f1;
        const uint32_t i2 = (uint32_t)f2;

        // hash components (uint32 wraparound multiply, primes {1, P1, P2})
        const uint32_t A0 = i0,            A1 = i0 + 1u;
        const uint32_t B0 = i1 * P1,       B1 = B0 + P1;
        const uint32_t C0 = i2 * P2,       C1 = C0 + P2;

        const float* tb = table + (((size_t)lvl << 19) << 1);  // lvl * T * F

        // corner order = meshgrid(ij): (a,b,c) with a slowest
        const uint32_t h000 = (A0 ^ B0 ^ C0) & TMASK;
        const uint32_t h001 = (A0 ^ B0 ^ C1) & TMASK;
        const uint32_t h010 = (A0 ^ B1 ^ C0) & TMASK;
        const uint32_t h011 = (A0 ^ B1 ^ C1) & TMASK;
        const uint32_t h100 = (A1 ^ B0 ^ C0) & TMASK;
        const uint32_t h101 = (A1 ^ B0 ^ C1) & TMASK;
        const uint32_t h110 = (A1 ^ B1 ^ C0) & TMASK;
        const uint32_t h111 = (A1 ^ B1 ^ C1) & TMASK;

        const float2 g000 = *(const float2*)(tb + 2 * (size_t)h000);
        const float2 g001 = *(const float2*)(tb + 2 * (size_t)h001);
        const float2 g010 = *(const float2*)(tb + 2 * (size_t)h010);
        const float2 g011 = *(const float2*)(tb + 2 * (size_t)h011);
        const float2 g100 = *(const float2*)(tb + 2 * (size_t)h100);
        const float2 g101 = *(const float2*)(tb + 2 * (size_t)h101);
        const float2 g110 = *(const float2*)(tb + 2 * (size_t)h110);
        const float2 g111 = *(const float2*)(tb + 2 * (size_t)h111);

        // trilinear weights, product order (d0*d1)*d2 like jnp.prod
        const float u0 = 1.0f - w0, u1 = 1.0f - w1, u2 = 1.0f - w2;
        const float wt000 = (u0 * u1) * u2;
        const float wt001 = (u0 * u1) * w2;
        const float wt010 = (u0 * w1) * u2;
        const float wt011 = (u0 * w1) * w2;
        const float wt100 = (w0 * u1) * u2;
        const float wt101 = (w0 * u1) * w2;
        const float wt110 = (w0 * w1) * u2;
        const float wt111 = (w0 * w1) * w2;

        float a0 = wt000 * g000.x;
        float a1 = wt000 * g000.y;
        a0 += wt001 * g001.x;  a1 += wt001 * g001.y;
        a0 += wt010 * g010.x;  a1 += wt010 * g010.y;
        a0 += wt011 * g011.x;  a1 += wt011 * g011.y;
        a0 += wt100 * g100.x;  a1 += wt100 * g100.y;
        a0 += wt101 * g101.x;  a1 += wt101 * g101.y;
        a0 += wt110 * g110.x;  a1 += wt110 * g110.y;
        a0 += wt111 * g111.x;  a1 += wt111 * g111.y;

        acc[2 * lvl + 0] = a0;
        acc[2 * lvl + 1] = a1;
    }

    // 128 B per thread, 16B-aligned vector stores
    float4* op = (float4*)(out + (size_t)n * 32);
#pragma unroll
    for (int k = 0; k < 8; ++k) {
        op[k] = make_float4(acc[4 * k + 0], acc[4 * k + 1],
                            acc[4 * k + 2], acc[4 * k + 3]);
    }
}

extern "C" void kernel_launch(void* const* d_in, const int* in_sizes, int n_in,
                              void* d_out, int out_size, void* d_ws, size_t ws_size,
                              hipStream_t stream) {
    const float* x     = (const float*)d_in[0];
    const float* table = (const float*)d_in[1];
    float* out         = (float*)d_out;

    // Reproduce Python's RESOLUTIONS bit-exactly using the same libm
    // (volatile fn pointers stop clang from folding/strength-reducing pow).
    double (*volatile p_log)(double)          = log;
    double (*volatile p_exp)(double)          = exp;
    double (*volatile p_pow)(double, double)  = pow;
    double (*volatile p_floor)(double)        = floor;

    const double b = p_exp((p_log(2048.0) - p_log(16.0)) / 15.0);
    ResArr ra;
    for (int i = 0; i < NLVL; ++i) {
        ra.r[i] = (int)p_floor(16.0 * p_pow(b, (double)i));
    }

    hashgrid_enc<<<NPTS / 256, 256, 0, stream>>>(x, table, out, ra);
}

// Round 2
// 697.921 us; speedup vs baseline: 1.1539x; 1.1539x over previous
//
#include <hip/hip_runtime.h>
#include <cmath>

#define NPTS   1048576
#define NLVL   16
#define TMASK  ((1u << 19) - 1u)
#define P1     2654435761u
#define P2     805459861u

typedef float v2f __attribute__((ext_vector_type(2)));

// One level per launch: the level's 4 MiB table is the only hot gather target,
// so it stays resident in every XCD's 4 MiB L2. x loads and out stores are
// non-temporal so streaming traffic doesn't evict table lines.
__global__ __launch_bounds__(256) void hashgrid_lvl(
    const float* __restrict__ x,
    const float* __restrict__ tb,     // table + lvl*T*F
    float* __restrict__ outl,         // out + 2*lvl
    float rf)
{
    const int n = blockIdx.x * 256 + threadIdx.x;   // NPTS % 256 == 0

    const float px = __builtin_nontemporal_load(x + 3 * (size_t)n + 0);
    const float py = __builtin_nontemporal_load(x + 3 * (size_t)n + 1);
    const float pz = __builtin_nontemporal_load(x + 3 * (size_t)n + 2);

    // must match fp32 reference arithmetic exactly (same as passing R1 kernel)
    const float xs0 = px * rf, xs1 = py * rf, xs2 = pz * rf;
    const float f0 = floorf(xs0), f1 = floorf(xs1), f2 = floorf(xs2);
    const float w0 = xs0 - f0, w1 = xs1 - f1, w2 = xs2 - f2;

    const uint32_t i0 = (uint32_t)f0;
    const uint32_t i1 = (uint32_t)f1;
    const uint32_t i2 = (uint32_t)f2;

    const uint32_t A0 = i0,      A1 = i0 + 1u;
    const uint32_t B0 = i1 * P1, B1 = B0 + P1;
    const uint32_t C0 = i2 * P2, C1 = C0 + P2;

    // corner order = meshgrid(ij): dim0 slowest
    const uint32_t h000 = (A0 ^ B0 ^ C0) & TMASK;
    const uint32_t h001 = (A0 ^ B0 ^ C1) & TMASK;
    const uint32_t h010 = (A0 ^ B1 ^ C0) & TMASK;
    const uint32_t h011 = (A0 ^ B1 ^ C1) & TMASK;
    const uint32_t h100 = (A1 ^ B0 ^ C0) & TMASK;
    const uint32_t h101 = (A1 ^ B0 ^ C1) & TMASK;
    const uint32_t h110 = (A1 ^ B1 ^ C0) & TMASK;
    const uint32_t h111 = (A1 ^ B1 ^ C1) & TMASK;

    const float2 g000 = *(const float2*)(tb + 2 * (size_t)h000);
    const float2 g001 = *(const float2*)(tb + 2 * (size_t)h001);
    const float2 g010 = *(const float2*)(tb + 2 * (size_t)h010);
    const float2 g011 = *(const float2*)(tb + 2 * (size_t)h011);
    const float2 g100 = *(const float2*)(tb + 2 * (size_t)h100);
    const float2 g101 = *(const float2*)(tb + 2 * (size_t)h101);
    const float2 g110 = *(const float2*)(tb + 2 * (size_t)h110);
    const float2 g111 = *(const float2*)(tb + 2 * (size_t)h111);

    const float u0 = 1.0f - w0, u1 = 1.0f - w1, u2 = 1.0f - w2;
    const float wt000 = (u0 * u1) * u2;
    const float wt001 = (u0 * u1) * w2;
    const float wt010 = (u0 * w1) * u2;
    const float wt011 = (u0 * w1) * w2;
    const float wt100 = (w0 * u1) * u2;
    const float wt101 = (w0 * u1) * w2;
    const float wt110 = (w0 * w1) * u2;
    const float wt111 = (w0 * w1) * w2;

    float a0 = wt000 * g000.x;
    float a1 = wt000 * g000.y;
    a0 += wt001 * g001.x;  a1 += wt001 * g001.y;
    a0 += wt010 * g010.x;  a1 += wt010 * g010.y;
    a0 += wt011 * g011.x;  a1 += wt011 * g011.y;
    a0 += wt100 * g100.x;  a1 += wt100 * g100.y;
    a0 += wt101 * g101.x;  a1 += wt101 * g101.y;
    a0 += wt110 * g110.x;  a1 += wt110 * g110.y;
    a0 += wt111 * g111.x;  a1 += wt111 * g111.y;

    v2f r; r.x = a0; r.y = a1;
    __builtin_nontemporal_store(r, (v2f*)(outl + (size_t)n * 32));
}

extern "C" void kernel_launch(void* const* d_in, const int* in_sizes, int n_in,
                              void* d_out, int out_size, void* d_ws, size_t ws_size,
                              hipStream_t stream) {
    const float* x     = (const float*)d_in[0];
    const float* table = (const float*)d_in[1];
    float* out         = (float*)d_out;

    // Reproduce Python's RESOLUTIONS bit-exactly using the same libm
    // (volatile fn pointers stop clang from folding/strength-reducing pow).
    double (*volatile p_log)(double)          = log;
    double (*volatile p_exp)(double)          = exp;
    double (*volatile p_pow)(double, double)  = pow;
    double (*volatile p_floor)(double)        = floor;

    const double b = p_exp((p_log(2048.0) - p_log(16.0)) / 15.0);

    for (int l = 0; l < NLVL; ++l) {
        const int res = (int)p_floor(16.0 * p_pow(b, (double)l));
        hashgrid_lvl<<<NPTS / 256, 256, 0, stream>>>(
            x,
            table + ((size_t)l << 20),   // l * T * F floats
            out + 2 * l,
            (float)res);
    }
}